// Round 2
// baseline (93.556 us; speedup 1.0000x reference)
//
#include <hip/hip_runtime.h>

__device__ __forceinline__ void se3_compute_and_store(
    float tx, float ty, float tz, float x, float y, float z,
    float4 e0, float4 e1, float4 e2, float4 e3,
    float4* O)
{
    // ---- se3 exp map coefficients (reference semantics: clip(dot, EPS)) ----
    float dot   = x*x + y*y + z*z;
    float t2    = fmaxf(dot, 1e-4f);
    float theta = sqrtf(t2);
    float inv   = 1.0f / theta;
    float s, c;
    sincosf(theta, &s, &c);
    float A  = s * inv;
    float Bc = (1.0f - c) * inv * inv;
    float Cc = (theta - s) * inv * inv * inv;

    float xx = x*x, yy = y*y, zz = z*z;
    float xy = x*y, xz = x*z, yz = y*z;

    // R = I + A*K + Bc*K^2
    float R00 = 1.0f - Bc*(yy + zz);
    float R01 = -A*z + Bc*xy;
    float R02 =  A*y + Bc*xz;
    float R10 =  A*z + Bc*xy;
    float R11 = 1.0f - Bc*(xx + zz);
    float R12 = -A*x + Bc*yz;
    float R20 = -A*y + Bc*xz;
    float R21 =  A*x + Bc*yz;
    float R22 = 1.0f - Bc*(xx + yy);

    // V = I + Bc*K + Cc*K^2
    float V00 = 1.0f - Cc*(yy + zz);
    float V01 = -Bc*z + Cc*xy;
    float V02 =  Bc*y + Cc*xz;
    float V10 =  Bc*z + Cc*xy;
    float V11 = 1.0f - Cc*(xx + zz);
    float V12 = -Bc*x + Cc*yz;
    float V20 = -Bc*y + Cc*xz;
    float V21 =  Bc*x + Cc*yz;
    float V22 = 1.0f - Cc*(xx + yy);

    // T = V @ t
    float T0 = V00*tx + V01*ty + V02*tz;
    float T1 = V10*tx + V11*ty + V12*tz;
    float T2 = V20*tx + V21*ty + V22*tz;

    float4 o0, o1, o2;
    o0.x = R00*e0.x + R01*e1.x + R02*e2.x + T0*e3.x;
    o0.y = R00*e0.y + R01*e1.y + R02*e2.y + T0*e3.y;
    o0.z = R00*e0.z + R01*e1.z + R02*e2.z + T0*e3.z;
    o0.w = R00*e0.w + R01*e1.w + R02*e2.w + T0*e3.w;

    o1.x = R10*e0.x + R11*e1.x + R12*e2.x + T1*e3.x;
    o1.y = R10*e0.y + R11*e1.y + R12*e2.y + T1*e3.y;
    o1.z = R10*e0.z + R11*e1.z + R12*e2.z + T1*e3.z;
    o1.w = R10*e0.w + R11*e1.w + R12*e2.w + T1*e3.w;

    o2.x = R20*e0.x + R21*e1.x + R22*e2.x + T2*e3.x;
    o2.y = R20*e0.y + R21*e1.y + R22*e2.y + T2*e3.y;
    o2.z = R20*e0.z + R21*e1.z + R22*e2.z + T2*e3.z;
    o2.w = R20*e0.w + R21*e1.w + R22*e2.w + T2*e3.w;

    O[0] = o0;
    O[1] = o1;
    O[2] = o2;
    O[3] = e3;
}

__global__ __launch_bounds__(256) void se3_apply_kernel2(
    const float* __restrict__ ext,   // [B,4,4]
    const float* __restrict__ se3,   // [N,6]
    const int*   __restrict__ idx,   // [B]
    float*       __restrict__ out,   // [B,4,4]
    int B)
{
    int base = blockIdx.x * 512 + threadIdx.x;
    int b0 = base;
    int b1 = base + 256;
    bool v0 = b0 < B;
    bool v1 = b1 < B;
    int c0 = v0 ? b0 : 0;     // clamped safe addresses for loads
    int c1 = v1 ? b1 : 0;

    // ---- issue both dependent gather chains back-to-back ----
    int j0 = idx[c0];
    int j1 = idx[c1];

    const float* w0 = se3 + (size_t)j0 * 6;
    const float* w1 = se3 + (size_t)j1 * 6;
    float2 a00 = *reinterpret_cast<const float2*>(w0 + 0);
    float2 a01 = *reinterpret_cast<const float2*>(w0 + 2);
    float2 a02 = *reinterpret_cast<const float2*>(w0 + 4);
    float2 a10 = *reinterpret_cast<const float2*>(w1 + 0);
    float2 a11 = *reinterpret_cast<const float2*>(w1 + 2);
    float2 a12 = *reinterpret_cast<const float2*>(w1 + 4);

    // ---- independent coalesced ext loads (can overlap the gathers) ----
    const float4* E0 = reinterpret_cast<const float4*>(ext + (size_t)c0 * 16);
    const float4* E1 = reinterpret_cast<const float4*>(ext + (size_t)c1 * 16);
    float4 e00 = E0[0], e01 = E0[1], e02 = E0[2], e03 = E0[3];
    float4 e10 = E1[0], e11 = E1[1], e12 = E1[2], e13 = E1[3];

    if (v0) {
        se3_compute_and_store(a00.x, a00.y, a01.x, a01.y, a02.x, a02.y,
                              e00, e01, e02, e03,
                              reinterpret_cast<float4*>(out + (size_t)b0 * 16));
    }
    if (v1) {
        se3_compute_and_store(a10.x, a10.y, a11.x, a11.y, a12.x, a12.y,
                              e10, e11, e12, e13,
                              reinterpret_cast<float4*>(out + (size_t)b1 * 16));
    }
}

extern "C" void kernel_launch(void* const* d_in, const int* in_sizes, int n_in,
                              void* d_out, int out_size, void* d_ws, size_t ws_size,
                              hipStream_t stream) {
    const float* ext = (const float*)d_in[0];   // [B,4,4]
    const float* se3 = (const float*)d_in[1];   // [N,6]
    const int*   idx = (const int*)d_in[2];     // [B]
    float* out = (float*)d_out;

    int B = in_sizes[2];
    int block = 256;
    int grid = (B + 512 - 1) / 512;
    se3_apply_kernel2<<<grid, block, 0, stream>>>(ext, se3, idx, out, B);
}

// Round 3
// 83.219 us; speedup vs baseline: 1.1242x; 1.1242x over previous
//
#include <hip/hip_runtime.h>

__global__ __launch_bounds__(256) void se3_apply_lds(
    const float* __restrict__ ext,   // [B,4,4]
    const float* __restrict__ se3,   // [N,6]
    const int*   __restrict__ idx,   // [B]
    float*       __restrict__ out,   // [B,4,4]
    int B)
{
    __shared__ float4 lds[1024];     // 16 KiB: 256 matrices
    const int t = threadIdx.x;
    const size_t mbase = (size_t)blockIdx.x * 256;   // first matrix of this block
    const int b  = (int)mbase + t;
    const int cb = (b < B) ? b : (B - 1);

    // ---- start the dependent gather chain FIRST (latency hides under staging) ----
    int j = idx[cb];

    // ---- cooperative lane-contiguous staging of 256 ext matrices ----
    const float4* extv = reinterpret_cast<const float4*>(ext);
    const size_t fbase = mbase * 4;          // float4 index of block start
    const size_t fmax  = (size_t)B * 4;
    size_t g0 = fbase + t;
    size_t g1 = fbase + t + 256;
    size_t g2 = fbase + t + 512;
    size_t g3 = fbase + t + 768;
    float4 s0 = extv[g0 < fmax ? g0 : 0];
    float4 s1 = extv[g1 < fmax ? g1 : 0];
    float4 s2 = extv[g2 < fmax ? g2 : 0];
    float4 s3 = extv[g3 < fmax ? g3 : 0];

    // ---- se3 row gather (dependent on j; overlaps with ext loads in flight) ----
    const float* w6 = se3 + (size_t)j * 6;
    float2 a0 = *reinterpret_cast<const float2*>(w6 + 0);
    float2 a1 = *reinterpret_cast<const float2*>(w6 + 2);
    float2 a2 = *reinterpret_cast<const float2*>(w6 + 4);

    lds[t      ] = s0;
    lds[t + 256] = s1;
    lds[t + 512] = s2;
    lds[t + 768] = s3;
    __syncthreads();

    // ---- each thread reads its own matrix from LDS ----
    float4 e0 = lds[t*4 + 0];
    float4 e1 = lds[t*4 + 1];
    float4 e2 = lds[t*4 + 2];
    float4 e3 = lds[t*4 + 3];

    // ---- se3 exp map (reference semantics: clip(dot, EPS)) ----
    float tx = a0.x, ty = a0.y, tz = a1.x;
    float x  = a1.y, y  = a2.x, z  = a2.y;

    float dot   = x*x + y*y + z*z;
    float theta = sqrtf(fmaxf(dot, 1e-4f));
    float inv   = 1.0f / theta;
    float s, c;
    sincosf(theta, &s, &c);
    float A  = s * inv;
    float Bc = (1.0f - c) * inv * inv;
    float Cc = (theta - s) * inv * inv * inv;

    float xx = x*x, yy = y*y, zz = z*z;
    float xy = x*y, xz = x*z, yz = y*z;

    float R00 = 1.0f - Bc*(yy + zz);
    float R01 = -A*z + Bc*xy;
    float R02 =  A*y + Bc*xz;
    float R10 =  A*z + Bc*xy;
    float R11 = 1.0f - Bc*(xx + zz);
    float R12 = -A*x + Bc*yz;
    float R20 = -A*y + Bc*xz;
    float R21 =  A*x + Bc*yz;
    float R22 = 1.0f - Bc*(xx + yy);

    float V00 = 1.0f - Cc*(yy + zz);
    float V01 = -Bc*z + Cc*xy;
    float V02 =  Bc*y + Cc*xz;
    float V10 =  Bc*z + Cc*xy;
    float V11 = 1.0f - Cc*(xx + zz);
    float V12 = -Bc*x + Cc*yz;
    float V20 = -Bc*y + Cc*xz;
    float V21 =  Bc*x + Cc*yz;
    float V22 = 1.0f - Cc*(xx + yy);

    float T0 = V00*tx + V01*ty + V02*tz;
    float T1 = V10*tx + V11*ty + V12*tz;
    float T2 = V20*tx + V21*ty + V22*tz;

    float4 o0, o1, o2;
    o0.x = R00*e0.x + R01*e1.x + R02*e2.x + T0*e3.x;
    o0.y = R00*e0.y + R01*e1.y + R02*e2.y + T0*e3.y;
    o0.z = R00*e0.z + R01*e1.z + R02*e2.z + T0*e3.z;
    o0.w = R00*e0.w + R01*e1.w + R02*e2.w + T0*e3.w;

    o1.x = R10*e0.x + R11*e1.x + R12*e2.x + T1*e3.x;
    o1.y = R10*e0.y + R11*e1.y + R12*e2.y + T1*e3.y;
    o1.z = R10*e0.z + R11*e1.z + R12*e2.z + T1*e3.z;
    o1.w = R10*e0.w + R11*e1.w + R12*e2.w + T1*e3.w;

    o2.x = R20*e0.x + R21*e1.x + R22*e2.x + T2*e3.x;
    o2.y = R20*e0.y + R21*e1.y + R22*e2.y + T2*e3.y;
    o2.z = R20*e0.z + R21*e1.z + R22*e2.z + T2*e3.z;
    o2.w = R20*e0.w + R21*e1.w + R22*e2.w + T2*e3.w;

    __syncthreads();           // all reads of staged ext done before overwrite

    lds[t*4 + 0] = o0;
    lds[t*4 + 1] = o1;
    lds[t*4 + 2] = o2;
    lds[t*4 + 3] = e3;         // bottom row of refinement is [0,0,0,1]
    __syncthreads();

    // ---- cooperative lane-contiguous store ----
    float4* outv = reinterpret_cast<float4*>(out);
    if (g0 < fmax) outv[g0] = lds[t      ];
    if (g1 < fmax) outv[g1] = lds[t + 256];
    if (g2 < fmax) outv[g2] = lds[t + 512];
    if (g3 < fmax) outv[g3] = lds[t + 768];
}

extern "C" void kernel_launch(void* const* d_in, const int* in_sizes, int n_in,
                              void* d_out, int out_size, void* d_ws, size_t ws_size,
                              hipStream_t stream) {
    const float* ext = (const float*)d_in[0];   // [B,4,4]
    const float* se3 = (const float*)d_in[1];   // [N,6]
    const int*   idx = (const int*)d_in[2];     // [B]
    float* out = (float*)d_out;

    int B = in_sizes[2];
    int block = 256;
    int grid = (B + 255) / 256;
    se3_apply_lds<<<grid, block, 0, stream>>>(ext, se3, idx, out, B);
}